// Round 10
// baseline (163.182 us; speedup 1.0000x reference)
//
#include <hip/hip_runtime.h>
#include <stdint.h>

#define L_SEQ 2048
#define B_SZ 2
#define NHH 8
#define HDD 128
#define C_SZ 1024
#define EMB_D 33
#define ORD 64
#define BANDS 16
#define FSTRIDE (L_SEQ + 256)   // 256 leading zeros per filter row for causal masking
#define FRS_S 2600              // FRS row stride (f16): 5200B spreads the 8 copies' banks
#define FRS_FILL 2176           // z in [0,2176) is the read range

typedef _Float16 f16;
typedef f16 f16x8 __attribute__((ext_vector_type(8)));
typedef float f32x4 __attribute__((ext_vector_type(4)));

// ---------------------------------------------------------------------------
// Kernel 1: hyena filter MLP -> filt[hd][FSTRIDE] f32 (row = 256 zeros | 2048 taps)
// filt[hd][lag 0] += D[hd]  (absorbs the kv*D term).
// ---------------------------------------------------------------------------
__global__ void filter_kernel(const float* __restrict__ w0, const float* __restrict__ b0,
                              const float* __restrict__ w1, const float* __restrict__ b1,
                              const float* __restrict__ w2, const float* __restrict__ b2,
                              const float* __restrict__ fr, const float* __restrict__ wf,
                              const float* __restrict__ md, const float* __restrict__ Dv,
                              float* __restrict__ filt) {
  int tid = threadIdx.x;
  int o = tid & 63;
  int lq = tid >> 6;                 // 0..3
  int l = blockIdx.x * 4 + lq;

  if (blockIdx.x < 128) filt[(size_t)blockIdx.x * FSTRIDE + tid] = 0.0f;

  __shared__ float zs[4][EMB_D];
  __shared__ float hs[4][ORD];
  __shared__ float gs[4][ORD];

  float t = (float)l / (float)(L_SEQ - 1);
  float wang = 6.2831853071795864f * (float)l / (float)L_SEQ;
  const float fstep = (15.0f - 1e-4f) / 15.0f;

  if (o == 0) zs[lq][0] = t;
  if (o >= 1 && o < 1 + BANDS) {
    int j = o - 1;
    float fj = 1e-4f + fstep * (float)j;
    zs[lq][1 + j] = cosf(wang * fj);
  }
  if (o >= 1 + BANDS && o < 1 + 2 * BANDS) {
    int j = o - 1 - BANDS;
    float fj = 1e-4f + fstep * (float)j;
    zs[lq][1 + BANDS + j] = -sinf(wang * fj);
  }
  __syncthreads();

  float fo = fr[o];
  float a = b0[o];
  for (int e = 0; e < EMB_D; ++e) a += zs[lq][e] * w0[o * EMB_D + e];
  hs[lq][o] = sinf(fo * a);
  __syncthreads();

  a = b1[o];
  for (int e = 0; e < ORD; ++e) a += hs[lq][e] * w1[o * ORD + e];
  gs[lq][o] = sinf(fo * a);
  __syncthreads();

  a = b2[o];
  for (int e = 0; e < ORD; ++e) a += gs[lq][e] * w2[o * ORD + e];
  float h3 = sinf(fo * a);
  __syncthreads();
  hs[lq][o] = h3;
  __syncthreads();

  #pragma unroll
  for (int pass = 0; pass < 2; ++pass) {
    int hd = pass * 64 + o;
    float acc = 0.0f;
    for (int e = 0; e < ORD; ++e) acc += hs[lq][e] * wf[hd * ORD + e];
    float val = acc * expf(-t * fabsf(md[hd]));
    if (l == 0) val += Dv[hd];   // absorb D term into lag-0 tap
    filt[(size_t)hd * FSTRIDE + 256 + l] = val;
  }
}

// ---------------------------------------------------------------------------
// Kernel 2: depthwise causal 3-tap conv + layout transform.
// q -> AqT[b][hd][n1][l]  f32 (transposed; epilogue reads float4 runs of l)
// k -> Akt16, v -> Avt16: chunk-blocked swizzled f16 tiles
//   [b][hd][chunk=l>>7][2048B]; elem (n, m=l&127) at byte n*256 + (2m ^ (n<<4))
// ---------------------------------------------------------------------------
#define TLC 64
__global__ void shortconv_kernel(const float* __restrict__ q_in,
                                 const float* __restrict__ k_in,
                                 const float* __restrict__ v_in,
                                 const float* __restrict__ scw,
                                 const float* __restrict__ scb,
                                 float* __restrict__ AqT, f16* __restrict__ Akt16,
                                 f16* __restrict__ Avt16) {
  int bid = blockIdx.x;
  int lt = bid & 31;
  int np = (bid >> 5) & 7;
  int b = bid >> 8;
  int l0 = lt * TLC;
  int tid = threadIdx.x;

  __shared__ float xs[TLC + 2][HDD + 4];
  __shared__ float wcs[HDD][4];

  const float* ins[3] = {q_in, k_in, v_in};

  for (int tsr = 0; tsr < 3; ++tsr) {
    const float* x = ins[tsr];
    if (tid < HDD) {
      int c = np * HDD + tid;
      wcs[tid][0] = scw[(tsr * C_SZ + c) * 3 + 0];
      wcs[tid][1] = scw[(tsr * C_SZ + c) * 3 + 1];
      wcs[tid][2] = scw[(tsr * C_SZ + c) * 3 + 2];
      wcs[tid][3] = scb[tsr * C_SZ + c];
    }
    for (int idx = tid; idx < (TLC + 2) * HDD; idx += 256) {
      int row = idx >> 7, hn = idx & 127;
      int l = l0 - 2 + row;
      float val = 0.0f;
      if (l >= 0) val = x[(((size_t)l * B_SZ + b) * NHH + np) * HDD + hn];
      xs[row][hn] = val;
    }
    __syncthreads();

    int n1 = tid & 7;
    int lp = tid >> 3;
    for (int hdi = 0; hdi < 16; ++hdi) {
      int hn = hdi * 8 + n1;
      float cw0 = wcs[hn][0], cw1 = wcs[hn][1], cw2 = wcs[hn][2], cb = wcs[hn][3];
      int hd = np * 16 + hdi;
      #pragma unroll
      for (int half = 0; half < 2; ++half) {
        int ll = half * 32 + lp;
        float y = cb + cw0 * xs[ll][hn] + cw1 * xs[ll + 1][hn]
                     + cw2 * xs[ll + 2][hn];
        int l = l0 + ll;
        if (tsr == 0) {
          AqT[(((size_t)b * HDD + hd) * NHH + n1) * L_SEQ + l] = y;
        } else {
          int ch = l >> 7, m = l & 127;
          int off = (n1 << 8) | ((m << 1) ^ (n1 << 4));   // swizzled byte in tile
          char* base = (tsr == 1) ? (char*)Akt16 : (char*)Avt16;
          *(f16*)(base + ((((size_t)(b * HDD + hd)) * 16 + ch) << 11) + off) = (f16)y;
        }
      }
    }
    __syncthreads();
  }
}

// ---------------------------------------------------------------------------
// Kernel 3 (MFMA v5, mt-split): per (b,hd):
//   G[l,n] = sum_{m<=l} W[l-m] * U[m,n],  U[m,n1*8+n2] = Av[m,n1]*Ak[m,n2]
//   out[l,n2] = sum_n1 Aq[l,n1] * G[l,n1*8+n2]
// Grid 2048 = (b, hd, pair pr): block processes tiles pr then 15-pr
// (17 chunks, perfectly balanced). ALL 4 waves work on every chunk of the
// current tile; wave w owns mt rows {w, w+4} (acc 32 VGPR, 6 af frags/unit,
// 100% wave-slot utilization, no cross-wave combine). 3 blocks/CU.
// DMA staging of pre-swizzled f16 tiles (R9). Epilogue reads AqT global (R8).
// mfma_f32_16x16x32_f16: A row=lane&15, k=(lane>>4)*8+e; B col=lane&15,
// k=(lane>>4)*8+e; C/D col=lane&15, row=(lane>>4)*4+reg.  (verified R6-R9)
// ---------------------------------------------------------------------------
__global__ void __launch_bounds__(256, 3)
hyena_main(const float* __restrict__ AqT, const f16* __restrict__ Akt16,
           const f16* __restrict__ Avt16, const float* __restrict__ filt,
           float* __restrict__ out) {
  int bid = blockIdx.x;            // 2048 = B * HD * 8
  int pr = bid & 7;
  int hd = (bid >> 3) & 127;
  int b  = bid >> 10;
  int tid = threadIdx.x;
  int w = tid >> 6;                // wave 0..3
  int lane = tid & 63;
  int r = lane & 15;               // A row / B col within 16
  int p = lane >> 4;               // k part 0..3
  int a = (15 - r) & 7;            // FRS shift-copy class

  __shared__ f16 FRS[8][FRS_S];    // FRS[a][z] = W[2047 - z - a]   (41600 B)
  __shared__ f16 AV[2][1024];      // swizzled [8n][128m] tile, dbuf (4 KB)
  __shared__ f16 AK[2][1024];      //                                (4 KB)

  const float* frow = filt + (size_t)hd * FSTRIDE + 256;   // lag-0
  const char* avtg = (const char*)Avt16 + (((size_t)(b * HDD + hd)) * 16 << 11);
  const char* aktg = (const char*)Akt16 + (((size_t)(b * HDD + hd)) * 16 << 11);
  const float* aqtb = AqT + ((size_t)b * HDD + hd) * NHH * L_SEQ;
  int np = hd >> 4, hnb = (hd & 15) * 8;

  // ---- stage FRS once; frow[-256..2047] valid (zero pad in front)
  for (int aa = 0; aa < 8; ++aa)
    for (int z = tid; z < FRS_FILL; z += 256)
      FRS[aa][z] = (f16)frow[2047 - z - aa];

  f32x4 acc[2][4];                 // [mi: mt=w / mt=w+4][nt]

  // DMA: wave w stages its 1KB segment (AV lo/hi, AK lo/hi)
  auto dma = [&](int c, int bi) {
    const char* srcb = (w >> 1) ? aktg : avtg;
    f16* dstb = (w >> 1) ? &AK[bi][(w & 1) * 512] : &AV[bi][(w & 1) * 512];
    const char* src = srcb + ((size_t)c << 11) + (w & 1) * 1024 + lane * 16;
    __builtin_amdgcn_global_load_lds((const unsigned int*)src,
                                     (unsigned int*)dstb, 16, 0, 0);
  };

  auto unit = [&](int lt, int c, int bi) {
    int dy = 2047 - (lt - c) * 128;
    // f[j] = FRS frag at dd = (3-w) + 2j ; mt=w uses f[s+2], mt=w+4 uses f[s]
    int zb = dy - r - a + p * 8 - 112 + 16 * (3 - w);
    f16x8 f[6];
    #pragma unroll
    for (int j = 0; j < 6; ++j)
      f[j] = *(const f16x8*)&FRS[a][zb + 32 * j];
    int ky = r & 7;
    __builtin_amdgcn_s_setprio(1);
    #pragma unroll
    for (int s = 0; s < 4; ++s) {
      f16x8 kf = *(const f16x8*)&AK[bi][ky * 128 + ((s * 32 + p * 8) ^ (ky * 8))];
      #pragma unroll
      for (int nt = 0; nt < 4; ++nt) {
        int vy = nt * 2 + (r >> 3);
        f16x8 vf = *(const f16x8*)&AV[bi][vy * 128 + ((s * 32 + p * 8) ^ (vy * 8))];
        f16x8 bf = vf * kf;                    // v_pk_mul_f16
        acc[0][nt] = __builtin_amdgcn_mfma_f32_16x16x32_f16(
            f[s + 2], bf, acc[0][nt], 0, 0, 0);   // mt = w
        acc[1][nt] = __builtin_amdgcn_mfma_f32_16x16x32_f16(
            f[s], bf, acc[1][nt], 0, 0, 0);       // mt = w+4
      }
    }
    __builtin_amdgcn_s_setprio(0);
  };

  auto epilogue = [&](int lt) {
    int l0 = lt * 128;
    int hi = r >> 3;
    int n2 = r & 7;
    #pragma unroll
    for (int mi = 0; mi < 2; ++mi) {
      int mt = w + 4 * mi;
      float4 qv[4];
      #pragma unroll
      for (int nt = 0; nt < 4; ++nt)
        qv[nt] = *(const float4*)(aqtb + (size_t)(nt * 2 + hi) * L_SEQ
                                  + l0 + mt * 16 + p * 4);
      #pragma unroll
      for (int reg = 0; reg < 4; ++reg) {
        float pv = qv[0][reg] * acc[mi][0][reg] + qv[1][reg] * acc[mi][1][reg]
                 + qv[2][reg] * acc[mi][2][reg] + qv[3][reg] * acc[mi][3][reg];
        pv += __shfl_xor(pv, 8, 64);
        if (r < 8) {
          int i = mt * 16 + p * 4 + reg;
          out[(((size_t)b * NHH + np) * L_SEQ + (l0 + i)) * HDD + hnb + n2] = pv;
        }
      }
    }
  };

  auto run_pass = [&](int lt, int NC) {
    #pragma unroll
    for (int mi = 0; mi < 2; ++mi)
      #pragma unroll
      for (int nt = 0; nt < 4; ++nt)
        acc[mi][nt] = f32x4{0.f, 0.f, 0.f, 0.f};
    dma(0, 0);
    for (int c = 0; c < NC; ++c) {
      __syncthreads();                 // dma(c) landed; prev reads done
      if (c + 1 < NC) dma(c + 1, (c + 1) & 1);   // in flight under unit(c)
      unit(lt, c, c & 1);
    }
    epilogue(lt);
    __syncthreads();                   // bufs reused by next pass
  };

  run_pass(pr, pr + 1);                // tile pr
  run_pass(15 - pr, 16 - pr);          // tile 15-pr  -> 17 chunks total, all blocks
}

// ---------------------------------------------------------------------------
extern "C" void kernel_launch(void* const* d_in, const int* in_sizes, int n_in,
                              void* d_out, int out_size, void* d_ws, size_t ws_size,
                              hipStream_t stream) {
  const float* q_in = (const float*)d_in[0];
  const float* k_in = (const float*)d_in[1];
  const float* v_in = (const float*)d_in[2];
  const float* scw  = (const float*)d_in[3];
  const float* scb  = (const float*)d_in[4];
  const float* Dv   = (const float*)d_in[5];
  const float* w0   = (const float*)d_in[6];
  const float* b0   = (const float*)d_in[7];
  const float* w1   = (const float*)d_in[8];
  const float* b1   = (const float*)d_in[9];
  const float* w2   = (const float*)d_in[10];
  const float* b2   = (const float*)d_in[11];
  const float* fr   = (const float*)d_in[12];
  const float* wf   = (const float*)d_in[13];
  const float* md   = (const float*)d_in[14];

  float* ws   = (float*)d_ws;
  float* filt = ws;                                        // 128*2304 f32
  float* AqT  = ws + (size_t)HDD * FSTRIDE;                // 2*128*2048*8 f32
  f16*   Akt16 = (f16*)(AqT + (size_t)B_SZ * HDD * L_SEQ * NHH);  // 4.19M f16
  f16*   Avt16 = Akt16 + (size_t)B_SZ * HDD * 16 * 1024;          // 4.19M f16

  filter_kernel<<<512, 256, 0, stream>>>(w0, b0, w1, b1, w2, b2, fr, wf, md, Dv, filt);
  shortconv_kernel<<<512, 256, 0, stream>>>(q_in, k_in, v_in, scw, scb, AqT, Akt16, Avt16);
  hyena_main<<<2048, 256, 0, stream>>>(AqT, Akt16, Avt16, filt, (float*)d_out);
}

// Round 11
// 148.396 us; speedup vs baseline: 1.0996x; 1.0996x over previous
//
#include <hip/hip_runtime.h>
#include <stdint.h>
#include <string.h>

#define L_SEQ 2048
#define B_SZ 2
#define NHH 8
#define HDD 128
#define C_SZ 1024
#define EMB_D 33
#define ORD 64
#define BANDS 16
#define FSTRIDE (L_SEQ + 256)   // 256 leading zeros per filter row for causal masking
#define FRS_S 2568              // FRS row stride (f16): 8-aligned, a*4-dword bank spread
#define FRS_FILL 2176           // z in [0,2176) is the read range

typedef _Float16 f16;
typedef f16 f16x8 __attribute__((ext_vector_type(8)));
typedef f16 f16x4 __attribute__((ext_vector_type(4)));
typedef float f32x4 __attribute__((ext_vector_type(4)));

// ---------------------------------------------------------------------------
// Kernel 1: hyena filter MLP -> filt[hd][FSTRIDE] f32 (row = 256 zeros | 2048 taps)
// filt[hd][lag 0] += D[hd]  (absorbs the kv*D term).
// ---------------------------------------------------------------------------
__global__ void filter_kernel(const float* __restrict__ w0, const float* __restrict__ b0,
                              const float* __restrict__ w1, const float* __restrict__ b1,
                              const float* __restrict__ w2, const float* __restrict__ b2,
                              const float* __restrict__ fr, const float* __restrict__ wf,
                              const float* __restrict__ md, const float* __restrict__ Dv,
                              float* __restrict__ filt) {
  int tid = threadIdx.x;
  int o = tid & 63;
  int lq = tid >> 6;                 // 0..3
  int l = blockIdx.x * 4 + lq;

  if (blockIdx.x < 128) filt[(size_t)blockIdx.x * FSTRIDE + tid] = 0.0f;

  __shared__ float zs[4][EMB_D];
  __shared__ float hs[4][ORD];
  __shared__ float gs[4][ORD];

  float t = (float)l / (float)(L_SEQ - 1);
  float wang = 6.2831853071795864f * (float)l / (float)L_SEQ;
  const float fstep = (15.0f - 1e-4f) / 15.0f;

  if (o == 0) zs[lq][0] = t;
  if (o >= 1 && o < 1 + BANDS) {
    int j = o - 1;
    float fj = 1e-4f + fstep * (float)j;
    zs[lq][1 + j] = cosf(wang * fj);
  }
  if (o >= 1 + BANDS && o < 1 + 2 * BANDS) {
    int j = o - 1 - BANDS;
    float fj = 1e-4f + fstep * (float)j;
    zs[lq][1 + BANDS + j] = -sinf(wang * fj);
  }
  __syncthreads();

  float fo = fr[o];
  float a = b0[o];
  for (int e = 0; e < EMB_D; ++e) a += zs[lq][e] * w0[o * EMB_D + e];
  hs[lq][o] = sinf(fo * a);
  __syncthreads();

  a = b1[o];
  for (int e = 0; e < ORD; ++e) a += hs[lq][e] * w1[o * ORD + e];
  gs[lq][o] = sinf(fo * a);
  __syncthreads();

  a = b2[o];
  for (int e = 0; e < ORD; ++e) a += gs[lq][e] * w2[o * ORD + e];
  float h3 = sinf(fo * a);
  __syncthreads();
  hs[lq][o] = h3;
  __syncthreads();

  #pragma unroll
  for (int pass = 0; pass < 2; ++pass) {
    int hd = pass * 64 + o;
    float acc = 0.0f;
    for (int e = 0; e < ORD; ++e) acc += hs[lq][e] * wf[hd * ORD + e];
    float val = acc * expf(-t * fabsf(md[hd]));
    if (l == 0) val += Dv[hd];   // absorb D term into lag-0 tap
    filt[(size_t)hd * FSTRIDE + 256 + l] = val;
  }
}

// ---------------------------------------------------------------------------
// Kernel 2: depthwise causal 3-tap conv + layout transform.
// q -> AqT[b][hd][n1][l]  f32 (transposed; epilogue reads float4 runs of l)
// k -> Akt16, v -> Avt16: chunk-blocked swizzled f16 tiles
//   [b][hd][chunk=l>>7][2048B]; elem (n, m=l&127) at byte n*256 + (2m ^ (n<<4))
// ---------------------------------------------------------------------------
#define TLC 64
__global__ void shortconv_kernel(const float* __restrict__ q_in,
                                 const float* __restrict__ k_in,
                                 const float* __restrict__ v_in,
                                 const float* __restrict__ scw,
                                 const float* __restrict__ scb,
                                 float* __restrict__ AqT, f16* __restrict__ Akt16,
                                 f16* __restrict__ Avt16) {
  int bid = blockIdx.x;
  int lt = bid & 31;
  int np = (bid >> 5) & 7;
  int b = bid >> 8;
  int l0 = lt * TLC;
  int tid = threadIdx.x;

  __shared__ float xs[TLC + 2][HDD + 4];
  __shared__ float wcs[HDD][4];

  const float* ins[3] = {q_in, k_in, v_in};

  for (int tsr = 0; tsr < 3; ++tsr) {
    const float* x = ins[tsr];
    if (tid < HDD) {
      int c = np * HDD + tid;
      wcs[tid][0] = scw[(tsr * C_SZ + c) * 3 + 0];
      wcs[tid][1] = scw[(tsr * C_SZ + c) * 3 + 1];
      wcs[tid][2] = scw[(tsr * C_SZ + c) * 3 + 2];
      wcs[tid][3] = scb[tsr * C_SZ + c];
    }
    for (int idx = tid; idx < (TLC + 2) * HDD; idx += 256) {
      int row = idx >> 7, hn = idx & 127;
      int l = l0 - 2 + row;
      float val = 0.0f;
      if (l >= 0) val = x[(((size_t)l * B_SZ + b) * NHH + np) * HDD + hn];
      xs[row][hn] = val;
    }
    __syncthreads();

    int n1 = tid & 7;
    int lp = tid >> 3;
    for (int hdi = 0; hdi < 16; ++hdi) {
      int hn = hdi * 8 + n1;
      float cw0 = wcs[hn][0], cw1 = wcs[hn][1], cw2 = wcs[hn][2], cb = wcs[hn][3];
      int hd = np * 16 + hdi;
      #pragma unroll
      for (int half = 0; half < 2; ++half) {
        int ll = half * 32 + lp;
        float y = cb + cw0 * xs[ll][hn] + cw1 * xs[ll + 1][hn]
                     + cw2 * xs[ll + 2][hn];
        int l = l0 + ll;
        if (tsr == 0) {
          AqT[(((size_t)b * HDD + hd) * NHH + n1) * L_SEQ + l] = y;
        } else {
          int ch = l >> 7, m = l & 127;
          int off = (n1 << 8) | ((m << 1) ^ (n1 << 4));   // swizzled byte in tile
          char* base = (tsr == 1) ? (char*)Akt16 : (char*)Avt16;
          *(f16*)(base + ((((size_t)(b * HDD + hd)) * 16 + ch) << 11) + off) = (f16)y;
        }
      }
    }
    __syncthreads();
  }
}

// ---------------------------------------------------------------------------
// Kernel 3 (MFMA v6): mt-split + XCD-shared + counted-vmcnt 3-buffer pipeline.
//   G[l,n] = sum_{m<=l} W[l-m] * U[m,n],  U[m,n1*8+n2] = Av[m,n1]*Ak[m,n2]
//   out[l,n2] = sum_n1 Aq[l,n1] * G[l,n1*8+n2]
// Slot decode: pr = bid>>8, (b,hd) = bid&255 -> the 8 pr-blocks of a (b,hd)
// share one XCD (slot%8 identical) -> Akt/Avt/FRS L2-resident per XCD.
// Chunk loop: raw s_barrier + s_waitcnt vmcnt(counted) (T4); 3 buffers,
// 2-deep prefetch -> dma has ~2 chunk-bodies of slack, never drains.
// mfma_f32_16x16x32_f16: A row=lane&15, k=(lane>>4)*8+e; B col=lane&15,
// k=(lane>>4)*8+e; C/D col=lane&15, row=(lane>>4)*4+reg.  (verified R6-R10)
// ---------------------------------------------------------------------------
__global__ void __launch_bounds__(256, 3)
hyena_main(const float* __restrict__ AqT, const f16* __restrict__ Akt16,
           const f16* __restrict__ Avt16, const float* __restrict__ filt,
           float* __restrict__ out) {
  int bid = blockIdx.x;            // 2048; slot = pr*256 + (b*128+hd)
  int pr = bid >> 8;
  int hd = bid & 127;
  int b  = (bid >> 7) & 1;
  int tid = threadIdx.x;
  int w = tid >> 6;                // wave 0..3
  int lane = tid & 63;
  int r = lane & 15;               // A row / B col within 16
  int p = lane >> 4;               // k part 0..3
  int a = (15 - r) & 7;            // FRS shift-copy class

  __shared__ f16 FRS[8][FRS_S];    // FRS[a][z] = W[2047 - z - a]   (41088 B)
  __shared__ f16 AV[3][1024];      // swizzled [8n][128m] tile, 3-buf (6 KB)
  __shared__ f16 AK[3][1024];      //                                (6 KB)

  const float* frow = filt + (size_t)hd * FSTRIDE + 256;   // lag-0
  const char* avtg = (const char*)Avt16 + (((size_t)(b * HDD + hd)) * 16 << 11);
  const char* aktg = (const char*)Akt16 + (((size_t)(b * HDD + hd)) * 16 << 11);
  const float* aqtb = AqT + ((size_t)b * HDD + hd) * NHH * L_SEQ;
  int np = hd >> 4, hnb = (hd & 15) * 8;

  // ---- stage FRS (vectorized): FRS[aa][z..z+3] = frow[2047-aa-z .. -3] reversed
  for (int aa = 0; aa < 8; ++aa) {
    for (int z4 = tid * 4; z4 < FRS_FILL; z4 += 1024) {
      const float* s = frow + (2044 - aa - z4);   // valid down to frow[-256]
      float4 v;
      __builtin_memcpy(&v, s, 16);                // 4B-aligned load
      f16x4 o = {(f16)v.w, (f16)v.z, (f16)v.y, (f16)v.x};
      *(f16x4*)&FRS[aa][z4] = o;
    }
  }

  f32x4 acc[2][4];                 // [mi: mt=w / mt=w+4][nt]

  // DMA: wave w stages its 1KB segment (AV lo/hi, AK lo/hi)
  auto dma = [&](int c, int bi) {
    const char* srcb = (w >> 1) ? aktg : avtg;
    f16* dstb = (w >> 1) ? &AK[bi][(w & 1) * 512] : &AV[bi][(w & 1) * 512];
    const char* src = srcb + ((size_t)c << 11) + (w & 1) * 1024 + lane * 16;
    __builtin_amdgcn_global_load_lds((const unsigned int*)src,
                                     (unsigned int*)dstb, 16, 0, 0);
  };

  auto unit = [&](int lt, int c, int bi) {
    int dy = 2047 - (lt - c) * 128;
    // f[j] = FRS frag at dd = (3-w) + 2j ; mt=w uses f[s+2], mt=w+4 uses f[s]
    int zb = dy - r - a + p * 8 - 112 + 16 * (3 - w);
    f16x8 f[6];
    #pragma unroll
    for (int j = 0; j < 6; ++j)
      f[j] = *(const f16x8*)&FRS[a][zb + 32 * j];
    int ky = r & 7;
    __builtin_amdgcn_s_setprio(1);
    #pragma unroll
    for (int s = 0; s < 4; ++s) {
      f16x8 kf = *(const f16x8*)&AK[bi][ky * 128 + ((s * 32 + p * 8) ^ (ky * 8))];
      #pragma unroll
      for (int nt = 0; nt < 4; ++nt) {
        int vy = nt * 2 + (r >> 3);
        f16x8 vf = *(const f16x8*)&AV[bi][vy * 128 + ((s * 32 + p * 8) ^ (vy * 8))];
        f16x8 bf = vf * kf;                    // v_pk_mul_f16
        acc[0][nt] = __builtin_amdgcn_mfma_f32_16x16x32_f16(
            f[s + 2], bf, acc[0][nt], 0, 0, 0);   // mt = w
        acc[1][nt] = __builtin_amdgcn_mfma_f32_16x16x32_f16(
            f[s], bf, acc[1][nt], 0, 0, 0);       // mt = w+4
      }
    }
    __builtin_amdgcn_s_setprio(0);
  };

  auto epilogue = [&](int lt) {
    int l0 = lt * 128;
    int hi = r >> 3;
    int n2 = r & 7;
    #pragma unroll
    for (int mi = 0; mi < 2; ++mi) {
      int mt = w + 4 * mi;
      float4 qv[4];
      #pragma unroll
      for (int nt = 0; nt < 4; ++nt)
        qv[nt] = *(const float4*)(aqtb + (size_t)(nt * 2 + hi) * L_SEQ
                                  + l0 + mt * 16 + p * 4);
      #pragma unroll
      for (int reg = 0; reg < 4; ++reg) {
        float pv = qv[0][reg] * acc[mi][0][reg] + qv[1][reg] * acc[mi][1][reg]
                 + qv[2][reg] * acc[mi][2][reg] + qv[3][reg] * acc[mi][3][reg];
        pv += __shfl_xor(pv, 8, 64);
        if (r < 8) {
          int i = mt * 16 + p * 4 + reg;
          out[(((size_t)b * NHH + np) * L_SEQ + (l0 + i)) * HDD + hnb + n2] = pv;
        }
      }
    }
  };

  auto run_pass = [&](int lt, int NC) {
    #pragma unroll
    for (int mi = 0; mi < 2; ++mi)
      #pragma unroll
      for (int nt = 0; nt < 4; ++nt)
        acc[mi][nt] = f32x4{0.f, 0.f, 0.f, 0.f};
    dma(0, 0);
    if (NC > 1) dma(1, 1);
    for (int c = 0; c < NC; ++c) {
      // counted wait: dma(c) landed; dma(c+1) may stay in flight (T4)
      if (c + 1 < NC)
        asm volatile("s_waitcnt vmcnt(1) lgkmcnt(0)" ::: "memory");
      else
        asm volatile("s_waitcnt vmcnt(0) lgkmcnt(0)" ::: "memory");
      __builtin_amdgcn_s_barrier();
      __builtin_amdgcn_sched_barrier(0);
      if (c + 2 < NC) {
        int bi2 = c + 2; bi2 -= (bi2 >= 3) ? 3 : 0; bi2 -= (bi2 >= 3) ? 3 : 0;
        dma(c + 2, (c + 2) % 3);
      }
      unit(lt, c, c % 3);
    }
    epilogue(lt);
    __syncthreads();                 // pass boundary: protect buffer reuse
  };

  run_pass(pr, pr + 1);              // tile pr
  run_pass(15 - pr, 16 - pr);        // tile 15-pr -> 17 chunks, all blocks equal
}

// ---------------------------------------------------------------------------
extern "C" void kernel_launch(void* const* d_in, const int* in_sizes, int n_in,
                              void* d_out, int out_size, void* d_ws, size_t ws_size,
                              hipStream_t stream) {
  const float* q_in = (const float*)d_in[0];
  const float* k_in = (const float*)d_in[1];
  const float* v_in = (const float*)d_in[2];
  const float* scw  = (const float*)d_in[3];
  const float* scb  = (const float*)d_in[4];
  const float* Dv   = (const float*)d_in[5];
  const float* w0   = (const float*)d_in[6];
  const float* b0   = (const float*)d_in[7];
  const float* w1   = (const float*)d_in[8];
  const float* b1   = (const float*)d_in[9];
  const float* w2   = (const float*)d_in[10];
  const float* b2   = (const float*)d_in[11];
  const float* fr   = (const float*)d_in[12];
  const float* wf   = (const float*)d_in[13];
  const float* md   = (const float*)d_in[14];

  float* ws   = (float*)d_ws;
  float* filt = ws;                                        // 128*2304 f32
  float* AqT  = ws + (size_t)HDD * FSTRIDE;                // 2*128*2048*8 f32
  f16*   Akt16 = (f16*)(AqT + (size_t)B_SZ * HDD * L_SEQ * NHH);  // 4.19M f16
  f16*   Avt16 = Akt16 + (size_t)B_SZ * HDD * 16 * 1024;          // 4.19M f16

  filter_kernel<<<512, 256, 0, stream>>>(w0, b0, w1, b1, w2, b2, fr, wf, md, Dv, filt);
  shortconv_kernel<<<512, 256, 0, stream>>>(q_in, k_in, v_in, scw, scb, AqT, Akt16, Avt16);
  hyena_main<<<2048, 256, 0, stream>>>(AqT, Akt16, Avt16, filt, (float*)d_out);
}

// Round 13
// 146.585 us; speedup vs baseline: 1.1132x; 1.0124x over previous
//
#include <hip/hip_runtime.h>
#include <stdint.h>
#include <string.h>

#define L_SEQ 2048
#define B_SZ 2
#define NHH 8
#define HDD 128
#define C_SZ 1024
#define EMB_D 33
#define ORD 64
#define BANDS 16
#define FSTRIDE (L_SEQ + 256)   // 256 leading zeros per filter row for causal masking
#define FRS_S 2184              // FRS row stride (f16): mod-64 = 8 -> 16B bank-phase walk
#define FRS_FILL 2176           // z in [0,2176) is the read range

typedef _Float16 f16;
typedef f16 f16x8 __attribute__((ext_vector_type(8)));
typedef f16 f16x4 __attribute__((ext_vector_type(4)));
typedef float f32x4 __attribute__((ext_vector_type(4)));

// ---------------------------------------------------------------------------
// Kernel 1: hyena filter MLP -> filt[hd][FSTRIDE] f32 (row = 256 zeros | 2048 taps)
// filt[hd][lag 0] += D[hd]  (absorbs the kv*D term).
// ---------------------------------------------------------------------------
__global__ void filter_kernel(const float* __restrict__ w0, const float* __restrict__ b0,
                              const float* __restrict__ w1, const float* __restrict__ b1,
                              const float* __restrict__ w2, const float* __restrict__ b2,
                              const float* __restrict__ fr, const float* __restrict__ wf,
                              const float* __restrict__ md, const float* __restrict__ Dv,
                              float* __restrict__ filt) {
  int tid = threadIdx.x;
  int o = tid & 63;
  int lq = tid >> 6;                 // 0..3
  int l = blockIdx.x * 4 + lq;

  if (blockIdx.x < 128) filt[(size_t)blockIdx.x * FSTRIDE + tid] = 0.0f;

  __shared__ float zs[4][EMB_D];
  __shared__ float hs[4][ORD];
  __shared__ float gs[4][ORD];

  float t = (float)l / (float)(L_SEQ - 1);
  float wang = 6.2831853071795864f * (float)l / (float)L_SEQ;
  const float fstep = (15.0f - 1e-4f) / 15.0f;

  if (o == 0) zs[lq][0] = t;
  if (o >= 1 && o < 1 + BANDS) {
    int j = o - 1;
    float fj = 1e-4f + fstep * (float)j;
    zs[lq][1 + j] = cosf(wang * fj);
  }
  if (o >= 1 + BANDS && o < 1 + 2 * BANDS) {
    int j = o - 1 - BANDS;
    float fj = 1e-4f + fstep * (float)j;
    zs[lq][1 + BANDS + j] = -sinf(wang * fj);
  }
  __syncthreads();

  float fo = fr[o];
  float a = b0[o];
  for (int e = 0; e < EMB_D; ++e) a += zs[lq][e] * w0[o * EMB_D + e];
  hs[lq][o] = sinf(fo * a);
  __syncthreads();

  a = b1[o];
  for (int e = 0; e < ORD; ++e) a += hs[lq][e] * w1[o * ORD + e];
  gs[lq][o] = sinf(fo * a);
  __syncthreads();

  a = b2[o];
  for (int e = 0; e < ORD; ++e) a += gs[lq][e] * w2[o * ORD + e];
  float h3 = sinf(fo * a);
  __syncthreads();
  hs[lq][o] = h3;
  __syncthreads();

  #pragma unroll
  for (int pass = 0; pass < 2; ++pass) {
    int hd = pass * 64 + o;
    float acc = 0.0f;
    for (int e = 0; e < ORD; ++e) acc += hs[lq][e] * wf[hd * ORD + e];
    float val = acc * expf(-t * fabsf(md[hd]));
    if (l == 0) val += Dv[hd];   // absorb D term into lag-0 tap
    filt[(size_t)hd * FSTRIDE + 256 + l] = val;
  }
}

// ---------------------------------------------------------------------------
// Kernel 2: depthwise causal 3-tap conv + layout transform.
// q -> AqT[b][hd][n1][l]  f32 (transposed; epilogue reads float4 runs of l)
// k -> Akt16, v -> Avt16: chunk-blocked swizzled f16 tiles
//   [b][hd][chunk=l>>7][2048B]; elem (n, m=l&127) at byte n*256 + (2m ^ (n<<4))
// ---------------------------------------------------------------------------
#define TLC 64
__global__ void shortconv_kernel(const float* __restrict__ q_in,
                                 const float* __restrict__ k_in,
                                 const float* __restrict__ v_in,
                                 const float* __restrict__ scw,
                                 const float* __restrict__ scb,
                                 float* __restrict__ AqT, f16* __restrict__ Akt16,
                                 f16* __restrict__ Avt16) {
  int bid = blockIdx.x;
  int lt = bid & 31;
  int np = (bid >> 5) & 7;
  int b = bid >> 8;
  int l0 = lt * TLC;
  int tid = threadIdx.x;

  __shared__ float xs[TLC + 2][HDD + 4];
  __shared__ float wcs[HDD][4];

  const float* ins[3] = {q_in, k_in, v_in};

  for (int tsr = 0; tsr < 3; ++tsr) {
    const float* x = ins[tsr];
    if (tid < HDD) {
      int c = np * HDD + tid;
      wcs[tid][0] = scw[(tsr * C_SZ + c) * 3 + 0];
      wcs[tid][1] = scw[(tsr * C_SZ + c) * 3 + 1];
      wcs[tid][2] = scw[(tsr * C_SZ + c) * 3 + 2];
      wcs[tid][3] = scb[tsr * C_SZ + c];
    }
    for (int idx = tid; idx < (TLC + 2) * HDD; idx += 256) {
      int row = idx >> 7, hn = idx & 127;
      int l = l0 - 2 + row;
      float val = 0.0f;
      if (l >= 0) val = x[(((size_t)l * B_SZ + b) * NHH + np) * HDD + hn];
      xs[row][hn] = val;
    }
    __syncthreads();

    int n1 = tid & 7;
    int lp = tid >> 3;
    for (int hdi = 0; hdi < 16; ++hdi) {
      int hn = hdi * 8 + n1;
      float cw0 = wcs[hn][0], cw1 = wcs[hn][1], cw2 = wcs[hn][2], cb = wcs[hn][3];
      int hd = np * 16 + hdi;
      #pragma unroll
      for (int half = 0; half < 2; ++half) {
        int ll = half * 32 + lp;
        float y = cb + cw0 * xs[ll][hn] + cw1 * xs[ll + 1][hn]
                     + cw2 * xs[ll + 2][hn];
        int l = l0 + ll;
        if (tsr == 0) {
          AqT[(((size_t)b * HDD + hd) * NHH + n1) * L_SEQ + l] = y;
        } else {
          int ch = l >> 7, m = l & 127;
          int off = (n1 << 8) | ((m << 1) ^ (n1 << 4));   // swizzled byte in tile
          char* base = (tsr == 1) ? (char*)Akt16 : (char*)Avt16;
          *(f16*)(base + ((((size_t)(b * HDD + hd)) * 16 + ch) << 11) + off) = (f16)y;
        }
      }
    }
    __syncthreads();
  }
}

// ---------------------------------------------------------------------------
// Kernel 3 (MFMA v8): dual-tile + dual-chunk merged loop, DEPTH-2 prefetch.
//   G[l,n] = sum_{m<=l} W[l-m] * U[m,n],  U[m,n1*8+n2] = Av[m,n1]*Ak[m,n2]
//   out[l,n2] = sum_n1 Aq[l,n1] * G[l,n1*8+n2]
// Block (pr, b, hd) owns tiles LT_hi=15-pr AND LT_lo=pr in ONE chunk loop:
// chunk c staged once, vf/kf read once, bf feeds up to 4 MFMA (hi always,
// lo when c<=pr). Loop step 2 (4 LDS bufs): one barrier per 2 chunks.
// BUFFER INVARIANT (R12 bug fix): DMA issued at iter `it` targets bufs
// (2it+2)&3,(2it+3)&3 which last held chunks 2it-2,2it-1 -- consumed before
// this iteration's barrier. Never overwrites a live buffer.
// XCD swizzle: slot = pr*256 + (b,hd) -> the 8 blocks of a (b,hd) share L2.
// mfma_f32_16x16x32_f16: A row=lane&15, k=(lane>>4)*8+e; B col=lane&15,
// k=(lane>>4)*8+e; C/D col=lane&15, row=(lane>>4)*4+reg.  (verified R6-R11)
// ---------------------------------------------------------------------------
__global__ void __launch_bounds__(256, 3)
hyena_main(const float* __restrict__ AqT, const f16* __restrict__ Akt16,
           const f16* __restrict__ Avt16, const float* __restrict__ filt,
           float* __restrict__ out) {
  int bid = blockIdx.x;            // 2048; slot = pr*256 + (b*128+hd)
  int pr = bid >> 8;               // 0..7
  int hd = bid & 127;
  int b  = (bid >> 7) & 1;
  int tid = threadIdx.x;
  int w = tid >> 6;                // wave 0..3
  int lane = tid & 63;
  int r = lane & 15;               // A row / B col within 16
  int p = lane >> 4;               // k part 0..3
  int a = (15 - r) & 7;            // FRS shift-copy class

  const int LT_hi = 15 - pr;
  const int LT_lo = pr;
  const int NCc = 16 - pr;         // chunks needed (>= 9)

  __shared__ f16 FRS[8][FRS_S];    // FRS[a][z] = W[2047 - z - a]   (34944 B)
  __shared__ f16 AV[4][1024];      // swizzled [8n][128m] tile, 4-buf (8 KB)
  __shared__ f16 AK[4][1024];      //                                (8 KB)

  const float* frow = filt + (size_t)hd * FSTRIDE + 256;   // lag-0
  const char* avtg = (const char*)Avt16 + (((size_t)(b * HDD + hd)) * 16 << 11);
  const char* aktg = (const char*)Akt16 + (((size_t)(b * HDD + hd)) * 16 << 11);
  const float* aqtb = AqT + ((size_t)b * HDD + hd) * NHH * L_SEQ;
  int np = hd >> 4, hnb = (hd & 15) * 8;

  // ---- stage FRS (vectorized); frow[-256..2047] valid (zero pad in front)
  for (int aa = 0; aa < 8; ++aa) {
    for (int z4 = tid * 4; z4 < FRS_FILL; z4 += 1024) {
      const float* s = frow + (2044 - aa - z4);
      float4 v;
      __builtin_memcpy(&v, s, 16);
      f16x4 o = {(f16)v.w, (f16)v.z, (f16)v.y, (f16)v.x};
      *(f16x4*)&FRS[aa][z4] = o;
    }
  }

  f32x4 aH[2][4], aL[2][4];
  #pragma unroll
  for (int mi = 0; mi < 2; ++mi)
    #pragma unroll
    for (int nt = 0; nt < 4; ++nt) {
      aH[mi][nt] = f32x4{0.f, 0.f, 0.f, 0.f};
      aL[mi][nt] = f32x4{0.f, 0.f, 0.f, 0.f};
    }

  // DMA: wave w stages its 1KB segment (AV lo/hi, AK lo/hi)
  auto dma = [&](int c, int bi) {
    const char* srcb = (w >> 1) ? aktg : avtg;
    f16* dstb = (w >> 1) ? &AK[bi][(w & 1) * 512] : &AV[bi][(w & 1) * 512];
    const char* src = srcb + ((size_t)c << 11) + (w & 1) * 1024 + lane * 16;
    __builtin_amdgcn_global_load_lds((const unsigned int*)src,
                                     (unsigned int*)dstb, 16, 0, 0);
  };

  // one chunk: shared bf, hi-tile always, lo-tile when c <= LT_lo (uniform)
  auto chunk_body = [&](int c) {
    int bi = c & 3;
    bool do_lo = (c <= LT_lo);
    int zcom = p * 8 - 112 + 16 * (3 - w) - r - a;
    int zbH = 2047 - (LT_hi - c) * 128 + zcom;
    f16x8 fH[6], fL[6];
    #pragma unroll
    for (int j = 0; j < 6; ++j)
      fH[j] = *(const f16x8*)&FRS[a][zbH + 32 * j];
    if (do_lo) {
      int zbL = 2047 - (LT_lo - c) * 128 + zcom;
      #pragma unroll
      for (int j = 0; j < 6; ++j)
        fL[j] = *(const f16x8*)&FRS[a][zbL + 32 * j];
    }
    int ky = r & 7;
    __builtin_amdgcn_s_setprio(1);
    #pragma unroll
    for (int s = 0; s < 4; ++s) {
      f16x8 kf = *(const f16x8*)&AK[bi][ky * 128 + ((s * 32 + p * 8) ^ (ky * 8))];
      #pragma unroll
      for (int nt = 0; nt < 4; ++nt) {
        int vy = nt * 2 + (r >> 3);
        f16x8 vf = *(const f16x8*)&AV[bi][vy * 128 + ((s * 32 + p * 8) ^ (vy * 8))];
        f16x8 bf = vf * kf;                    // v_pk_mul_f16
        aH[0][nt] = __builtin_amdgcn_mfma_f32_16x16x32_f16(
            fH[s + 2], bf, aH[0][nt], 0, 0, 0);   // hi, mt = w
        aH[1][nt] = __builtin_amdgcn_mfma_f32_16x16x32_f16(
            fH[s], bf, aH[1][nt], 0, 0, 0);       // hi, mt = w+4
        if (do_lo) {
          aL[0][nt] = __builtin_amdgcn_mfma_f32_16x16x32_f16(
              fL[s + 2], bf, aL[0][nt], 0, 0, 0); // lo, mt = w
          aL[1][nt] = __builtin_amdgcn_mfma_f32_16x16x32_f16(
              fL[s], bf, aL[1][nt], 0, 0, 0);     // lo, mt = w+4
        }
      }
    }
    __builtin_amdgcn_s_setprio(0);
  };

  auto epilogue = [&](int lt, f32x4 (&acc)[2][4]) {
    int l0 = lt * 128;
    int hi = r >> 3;
    int n2 = r & 7;
    #pragma unroll
    for (int mi = 0; mi < 2; ++mi) {
      int mt = w + 4 * mi;
      float4 qv[4];
      #pragma unroll
      for (int nt = 0; nt < 4; ++nt)
        qv[nt] = *(const float4*)(aqtb + (size_t)(nt * 2 + hi) * L_SEQ
                                  + l0 + mt * 16 + p * 4);
      #pragma unroll
      for (int reg = 0; reg < 4; ++reg) {
        float pv = qv[0][reg] * acc[mi][0][reg] + qv[1][reg] * acc[mi][1][reg]
                 + qv[2][reg] * acc[mi][2][reg] + qv[3][reg] * acc[mi][3][reg];
        pv += __shfl_xor(pv, 8, 64);
        if (r < 8) {
          int i = mt * 16 + p * 4 + reg;
          out[(((size_t)b * NHH + np) * L_SEQ + (l0 + i)) * HDD + hnb + n2] = pv;
        }
      }
    }
  };

  // prologue: 2 chunks in flight (depth-2; NCc >= 9 so no guards needed)
  dma(0, 0); dma(1, 1);

  int iters = (NCc + 1) >> 1;
  for (int it = 0; it < iters; ++it) {
    int c0 = 2 * it, c1 = 2 * it + 1;
    // dma(c0), dma(c1) (issued last iter) must land; FRS writes visible.
    asm volatile("s_waitcnt vmcnt(0) lgkmcnt(0)" ::: "memory");
    __builtin_amdgcn_s_barrier();
    __builtin_amdgcn_sched_barrier(0);
    // depth-2 prefetch: targets bufs that held chunks 2it-2, 2it-1 --
    // consumed before the barrier above (R12 fix).
    if (c0 + 2 < NCc) dma(c0 + 2, (c0 + 2) & 3);
    if (c1 + 2 < NCc) dma(c1 + 2, (c1 + 2) & 3);
    chunk_body(c0);
    if (c1 < NCc) chunk_body(c1);
  }

  epilogue(LT_hi, aH);
  epilogue(LT_lo, aL);
}

// ---------------------------------------------------------------------------
extern "C" void kernel_launch(void* const* d_in, const int* in_sizes, int n_in,
                              void* d_out, int out_size, void* d_ws, size_t ws_size,
                              hipStream_t stream) {
  const float* q_in = (const float*)d_in[0];
  const float* k_in = (const float*)d_in[1];
  const float* v_in = (const float*)d_in[2];
  const float* scw  = (const float*)d_in[3];
  const float* scb  = (const float*)d_in[4];
  const float* Dv   = (const float*)d_in[5];
  const float* w0   = (const float*)d_in[6];
  const float* b0   = (const float*)d_in[7];
  const float* w1   = (const float*)d_in[8];
  const float* b1   = (const float*)d_in[9];
  const float* w2   = (const float*)d_in[10];
  const float* b2   = (const float*)d_in[11];
  const float* fr   = (const float*)d_in[12];
  const float* wf   = (const float*)d_in[13];
  const float* md   = (const float*)d_in[14];

  float* ws   = (float*)d_ws;
  float* filt = ws;                                        // 128*2304 f32
  float* AqT  = ws + (size_t)HDD * FSTRIDE;                // 2*128*2048*8 f32
  f16*   Akt16 = (f16*)(AqT + (size_t)B_SZ * HDD * L_SEQ * NHH);  // 4.19M f16
  f16*   Avt16 = Akt16 + (size_t)B_SZ * HDD * 16 * 1024;          // 4.19M f16

  filter_kernel<<<512, 256, 0, stream>>>(w0, b0, w1, b1, w2, b2, fr, wf, md, Dv, filt);
  shortconv_kernel<<<512, 256, 0, stream>>>(q_in, k_in, v_in, scw, scb, AqT, Akt16, Avt16);
  hyena_main<<<2048, 256, 0, stream>>>(AqT, Akt16, Avt16, filt, (float*)d_out);
}